// Round 1
// 666.811 us; speedup vs baseline: 1.5407x; 1.5407x over previous
//
#include <hip/hip_runtime.h>
#include <math.h>
#include <limits.h>

#define BSZ 16
#define NQ  900
#define NCL 92
#define NT  256
#define SUMT (BSZ*NT)   /* 4096 */
#define MM  NQ          /* JV columns (queries) */
#define NN  NT          /* JV rows (targets)    */
#define NSLOT 15        /* ceil(900/64) columns per lane */
#define QCHUNK 60       /* q's per cost block: 900 = 15*60 */

// ---------------------------------------------------------------------------
// Kernel A: softmax probs, one wave per (b,q) row, shuffle-only.
// ---------------------------------------------------------------------------
__global__ __launch_bounds__(256) void prob_kernel(
    const float* __restrict__ logits, float* __restrict__ P) {
#pragma clang fp contract(off)
  const int w = threadIdx.x >> 6, lane = threadIdx.x & 63;
  const int r = blockIdx.x * 4 + w;
  const size_t base = (size_t)r * NCL;
  const float x1 = logits[base + lane];
  const float x2 = (lane + 64 < NCL) ? logits[base + lane + 64] : -INFINITY;
  float m = fmaxf(x1, x2);
  #pragma unroll
  for (int k = 1; k < 64; k <<= 1) m = fmaxf(m, __shfl_xor(m, k));
  const float e1 = expf(x1 - m);
  const float e2 = (lane + 64 < NCL) ? expf(x2 - m) : 0.f;
  float ssum = e1 + e2;
  #pragma unroll
  for (int k = 1; k < 64; k <<= 1) ssum += __shfl_xor(ssum, k);
  P[base + lane] = e1 / ssum;
  if (lane + 64 < NCL) P[base + lane + 64] = e2 / ssum;
}

// ---------------------------------------------------------------------------
// Kernel B: cost matrix, coalesced stores; per-block LDS staging of the
// 60 query boxes + 60x92 prob rows so the q-loop is LDS+VALU only.
// ---------------------------------------------------------------------------
__global__ __launch_bounds__(256) void cost_kernel2(
    const float* __restrict__ P, const float* __restrict__ boxes,
    const int* __restrict__ labels, const float* __restrict__ tbox,
    float* __restrict__ C) {
#pragma clang fp contract(off)
  const int tid = threadIdx.x;
  const int jt = blockIdx.x * 256 + tid;
  const int b  = blockIdx.z;
  const int q0 = blockIdx.y * QCHUNK;

  __shared__ float sP[QCHUNK * NCL];   // 5520 floats
  __shared__ float sB[QCHUNK * 4];     // 240 floats

  const size_t pbase = (size_t)(b * NQ + q0) * NCL;
  for (int x = tid; x < QCHUNK * NCL; x += 256) sP[x] = P[pbase + x];
  const size_t bbase = (size_t)(b * NQ + q0) * 4;
  if (tid < QCHUNK * 4) sB[tid] = boxes[bbase + tid];

  const float4 tb = ((const float4*)tbox)[jt];
  const int lab = labels[jt];
  const float tx1 = tb.x - 0.5f*tb.z, ty1 = tb.y - 0.5f*tb.w;
  const float tx2 = tb.x + 0.5f*tb.z, ty2 = tb.y + 0.5f*tb.w;
  const float area2 = (tx2 - tx1) * (ty2 - ty1);
  __syncthreads();

  for (int qq = 0; qq < QCHUNK; ++qq) {
    const float cx = sB[qq*4+0], cy = sB[qq*4+1];
    const float w  = sB[qq*4+2], h  = sB[qq*4+3];
    const float cc = -sP[qq*NCL + lab];
    const float bx1 = cx - 0.5f*w, by1 = cy - 0.5f*h;
    const float bx2 = cx + 0.5f*w, by2 = cy + 0.5f*h;
    const float area1 = (bx2 - bx1) * (by2 - by1);
    const float d0 = fabsf(cx - tb.x), d1 = fabsf(cy - tb.y);
    const float d2 = fabsf(w - tb.z),  d3 = fabsf(h - tb.w);
    const float cb = ((d0 + d1) + d2) + d3;
    const float ltx = fmaxf(bx1, tx1), lty = fmaxf(by1, ty1);
    const float rbx = fminf(bx2, tx2), rby = fminf(by2, ty2);
    const float iw = fmaxf(rbx - ltx, 0.f), ih = fmaxf(rby - lty, 0.f);
    const float inter = iw * ih;
    const float uni = (area1 + area2) - inter;
    const float iou = inter / uni;
    const float ex1 = fminf(bx1, tx1), ey1 = fminf(by1, ty1);
    const float ex2 = fmaxf(bx2, tx2), ey2 = fmaxf(by2, ty2);
    const float ew = fmaxf(ex2 - ex1, 0.f), eh = fmaxf(ey2 - ey1, 0.f);
    const float ea = ew * eh;
    const float giou = iou - (ea - uni) / ea;
    C[(size_t)(b*NQ + q0 + qq) * SUMT + jt] = (5.0f*cb + 1.0f*cc) + 2.0f*(-giou);
  }
}

// ---------------------------------------------------------------------------
// Kernel C: LDS-tiled transpose of the diagonal slabs: costT[b][t][q].
// ---------------------------------------------------------------------------
__global__ __launch_bounds__(256) void transpose_kernel(
    const float* __restrict__ C, float* __restrict__ costT) {
  __shared__ float tile[64][65];
  const int b  = blockIdx.z;
  const int q0 = blockIdx.x * 64, t0 = blockIdx.y * 64;
  const int tx = threadIdx.x & 63, ty = threadIdx.x >> 6;
  #pragma unroll
  for (int i = 0; i < 16; ++i) {
    const int qq = ty + i*4;
    const int q = q0 + qq;
    if (q < NQ)
      tile[qq][tx] = C[((size_t)(b*NQ + q))*SUMT + b*NT + t0 + tx];
  }
  __syncthreads();
  #pragma unroll
  for (int i = 0; i < 16; ++i) {
    const int tt = ty + i*4;
    const int q = q0 + tx;
    if (q < NQ)
      costT[((size_t)(b*NT + t0 + tt))*MM + q] = tile[tx][tt];
  }
}

// ---------------------------------------------------------------------------
// Fallback cost kernel (used only if workspace is too small).
// ---------------------------------------------------------------------------
__global__ __launch_bounds__(256) void cost_kernel_fb(
    const float* __restrict__ logits, const float* __restrict__ boxes,
    const int* __restrict__ labels, const float* __restrict__ tbox,
    float* __restrict__ C, float* __restrict__ costT) {
#pragma clang fp contract(off)
  const int bq  = blockIdx.x;
  const int b   = bq / NQ;
  const int tid = threadIdx.x;
  __shared__ float lg[NCL];
  __shared__ float red[128];
  if (tid < NCL) lg[tid] = logits[(size_t)bq * NCL + tid];
  __syncthreads();
  if (tid < 128) red[tid] = (tid < NCL) ? lg[tid] : -INFINITY;
  __syncthreads();
  for (int s = 64; s > 0; s >>= 1) { if (tid < s) red[tid] = fmaxf(red[tid], red[tid+s]); __syncthreads(); }
  const float mx = red[0];
  __syncthreads();
  float e = 0.f;
  if (tid < NCL) e = expf(lg[tid] - mx);
  if (tid < 128) red[tid] = e;
  __syncthreads();
  for (int s = 64; s > 0; s >>= 1) { if (tid < s) red[tid] += red[tid+s]; __syncthreads(); }
  const float sm = red[0];
  __syncthreads();
  if (tid < NCL) lg[tid] = e / sm;
  __syncthreads();
  const float cx = boxes[(size_t)bq*4+0], cy = boxes[(size_t)bq*4+1];
  const float w  = boxes[(size_t)bq*4+2], h  = boxes[(size_t)bq*4+3];
  const float bx1 = cx - 0.5f*w, by1 = cy - 0.5f*h;
  const float bx2 = cx + 0.5f*w, by2 = cy + 0.5f*h;
  const float area1 = (bx2 - bx1) * (by2 - by1);
  const int q = bq - b * NQ;
  for (int jt = tid; jt < SUMT; jt += 256) {
    const float4 tb = ((const float4*)tbox)[jt];
    const int lab = labels[jt];
    const float cc = -lg[lab];
    const float d0 = fabsf(cx - tb.x), d1 = fabsf(cy - tb.y);
    const float d2 = fabsf(w - tb.z),  d3 = fabsf(h - tb.w);
    const float cb = ((d0 + d1) + d2) + d3;
    const float tx1 = tb.x - 0.5f*tb.z, ty1 = tb.y - 0.5f*tb.w;
    const float tx2 = tb.x + 0.5f*tb.z, ty2 = tb.y + 0.5f*tb.w;
    const float area2 = (tx2 - tx1) * (ty2 - ty1);
    const float ltx = fmaxf(bx1, tx1), lty = fmaxf(by1, ty1);
    const float rbx = fminf(bx2, tx2), rby = fminf(by2, ty2);
    const float iw = fmaxf(rbx - ltx, 0.f), ih = fmaxf(rby - lty, 0.f);
    const float inter = iw * ih;
    const float uni = (area1 + area2) - inter;
    const float iou = inter / uni;
    const float ex1 = fminf(bx1, tx1), ey1 = fminf(by1, ty1);
    const float ex2 = fmaxf(bx2, tx2), ey2 = fmaxf(by2, ty2);
    const float ew = fmaxf(ex2 - ex1, 0.f), eh = fmaxf(ey2 - ey1, 0.f);
    const float ea = ew * eh;
    const float giou = iou - (ea - uni) / ea;
    const float cval = (5.0f*cb + 1.0f*cc) + 2.0f*(-giou);
    C[(size_t)bq * SUMT + jt] = cval;
    if (costT && (jt >> 8) == b) costT[(size_t)jt * MM + q] = cval;
  }
}

// ---------------------------------------------------------------------------
// Kernel D: JV LSA with greedy dual init + augmenting row reduction (ARR) +
// shifted-space Dijkstra cleanup.
// Phase A (256 thr): row-min duals u[i]=min_j c[i][j] (exact f32 min) +
//   greedy claim of argmin columns (lowest-row-wins == sequential greedy).
// Phase A2 (wave 0): JV augmenting-row-reduction for the ~36 unclaimed rows:
//   one wave-parallel scan finds (mu1@j1, mu2); set u[i]=mu2, v[j1]-=mu2-mu1,
//   steal j1, chain with the displaced row until a free column is hit.
//   Invariants maintained exactly (doubles): dual feasibility (v only
//   decreases; reduced costs stay >=0) and complementary slackness (assigned
//   pairs at reduced cost 0; columns with v<0 stay matched). Hence if ARR
//   completes, the assignment is optimal; any rows left free (step cap /
//   exact ties) are finished by the Dijkstra phase, which only needs those
//   invariants.
// Phase B (wave 0): Dijkstra for remaining unassigned rows, lazy deltas:
//   M[j] = minv[j] + sum(delta) is invariant; dual updates batched at the
//   end over the used-list. Finds the same (a.s. unique) optimum as ref.
// ---------------------------------------------------------------------------
__global__ __launch_bounds__(256) void lsa_kernel(
    const float* __restrict__ C, const float* __restrict__ costT,
    float* __restrict__ rows_out, float* __restrict__ cols_out) {
  const int b   = blockIdx.x;
  const int tid = threadIdx.x;

  __shared__ double u[NN + 1];
  __shared__ int    p[MM + 1];
  __shared__ int    wayl[MM + 1];
  __shared__ int    claim[MM + 1];
  __shared__ int    rowargmin[NN];
  __shared__ unsigned char rowass[NN];
  __shared__ int    listj[MM + 1];
  __shared__ double listD[MM + 1];

  // ---- Phase A: row minima + greedy claims (all 256 threads) ----
  for (int j = tid; j <= MM; j += 256) { p[j] = 0; claim[j] = INT_MAX; }
  {
    const float* rowptr = C + ((size_t)(b * NQ)) * SUMT + b * NT + tid;
    float mn = INFINITY; int am = 0;
    #pragma unroll 4
    for (int q = 0; q < NQ; ++q) {
      const float cv = rowptr[(size_t)q * SUMT];
      if (cv < mn) { mn = cv; am = q; }
    }
    u[tid + 1] = (double)mn;     // exact: pure f32 min, no arithmetic
    rowargmin[tid] = am;
  }
  if (tid == 0) u[0] = 0.0;
  __syncthreads();
  atomicMin(&claim[rowargmin[tid] + 1], tid + 1);
  __syncthreads();
  {
    const int am = rowargmin[tid];
    const bool got = (claim[am + 1] == tid + 1);
    rowass[tid] = got ? 1 : 0;
    if (got) p[am + 1] = tid + 1;
  }
  __syncthreads();
  if (tid >= 64) return;                   // phases A2/B are wave 0 only

  const int lane = tid;
  const float* slab = costT ? costT + (size_t)b * NT * MM : nullptr;
  double v_r[NSLOT];
  #pragma unroll
  for (int s = 0; s < NSLOT; ++s) v_r[s] = 0.0;

  // ---- Phase A2: augmenting row reduction (wave 0) ----
  if (slab) {
    int steps = 0;
    const int ARR_CAP = 2048;
    for (int i0 = 1; i0 <= NN && steps < ARR_CAP; ++i0) {
      if (rowass[i0 - 1]) continue;
      int i = i0;
      while (steps < ARR_CAP) {
        ++steps;
        const float* rowp = slab + (size_t)(i - 1) * MM;
        double b1 = INFINITY, b2 = INFINITY; int j1 = MM + 2;
        #pragma unroll
        for (int s = 0; s < NSLOT; ++s) {
          const int j = s * 64 + lane + 1;
          if (j <= MM) {
            const double cand = (double)rowp[j - 1] - v_r[s];
            if (cand < b1) { b2 = b1; b1 = cand; j1 = j; }
            else           { b2 = fmin(b2, cand); }
          }
        }
        #pragma unroll
        for (int m = 1; m < 64; m <<= 1) {
          const double ob1 = __shfl_xor(b1, m);
          const double ob2 = __shfl_xor(b2, m);
          const int    oj1 = __shfl_xor(j1, m);
          if (ob1 < b1 || (ob1 == b1 && oj1 < j1)) {
            b2 = fmin(b1, ob2); b1 = ob1; j1 = oj1;
          } else {
            b2 = fmin(b2, ob1);
          }
        }
        // all lanes agree: b1 = mu1 at column j1, b2 = mu2 (>= mu1)
        const double amt = ((b2 < INFINITY) ? b2 : b1) - b1;   // mu2 - mu1
        if (lane == ((j1 - 1) & 63)) v_r[(j1 - 1) >> 6] -= amt;
        const int k = p[j1];                 // read before overwrite
        if (lane == 0) {
          u[i] = b1 + amt;                   // u[i] = mu2 (equality at j1)
          p[j1] = i;
          rowass[i - 1] = 1;
          if (k != 0) rowass[k - 1] = 0;
        }
        if (k == 0) break;                   // chain ended at a free column
        i = k;
      }
    }
  }

  // ---- Phase B: Dijkstra for any remaining unassigned rows (wave 0) ----
  for (int ii = 1; ii <= NN; ++ii) {
    if (rowass[ii - 1]) continue;

    double M_r[NSLOT];
    #pragma unroll
    for (int s = 0; s < NSLOT; ++s) M_r[s] = INFINITY;
    unsigned int used = (lane < 4) ? 0u : (1u << 14);  // kill slot-14 tail
    int    lcount = 0;
    int    j0 = 0;
    double Dsel = 0.0;          // D at j0's selection (0 for virtual col)
    double D = 0.0;

    while (true) {
      const int    i0 = (j0 == 0) ? ii : p[j0];
      const double us = u[i0] - Dsel;
      const float* rowp = slab ? slab + (size_t)(i0 - 1) * MM : nullptr;

      double best = INFINITY; int bestj = MM + 2;
      #pragma unroll
      for (int s = 0; s < NSLOT; ++s) {
        if (!(used & (1u << s))) {
          const int j = s * 64 + lane + 1;
          const float cf = rowp ? rowp[j - 1]
              : C[((size_t)(b*NQ + (j-1)))*SUMT + (b*NT + i0 - 1)];
          const double cand = ((double)cf - v_r[s]) - us;
          if (cand < M_r[s]) { M_r[s] = cand; wayl[j] = j0; }
          if (M_r[s] < best) { best = M_r[s]; bestj = j; }
        }
      }
      #pragma unroll
      for (int m = 1; m < 64; m <<= 1) {
        const double ov = __shfl_xor(best, m);
        const int    oj = __shfl_xor(bestj, m);
        if (ov < best || (ov == best && oj < bestj)) { best = ov; bestj = oj; }
      }
      const int j1 = bestj;
      D = best;                                  // accumulated delta = M[j1]
      if (lane == ((j1 - 1) & 63)) used |= 1u << ((j1 - 1) >> 6);
      if (p[j1] == 0) { j0 = j1; break; }        // free column: done
      if (lane == 0) { listj[lcount] = j1; listD[lcount] = D; }
      lcount++;
      j0 = j1; Dsel = D;
    }

    // batched dual updates (old p), then augmentation
    for (int e = 0; e < lcount; ++e) {
      const int    je = listj[e];
      const double amt = D - listD[e];
      if (lane == ((je - 1) & 63)) v_r[(je - 1) >> 6] -= amt;
      if (lane == 0) u[p[je]] += amt;
    }
    if (lane == 0) {
      u[ii] += D;                                // virtual column j0=0
      int jj = j0;
      while (jj) { const int jn = wayl[jj]; const int pn = (jn == 0) ? ii : p[jn]; p[jj] = pn; jj = jn; }
      rowass[ii - 1] = 1;
    }
  }

  // ---- emit (query, target) pairs in ascending query order ----
  int base = 0;
  #pragma unroll
  for (int s = 0; s < NSLOT; ++s) {
    const int j = s * 64 + lane + 1;
    const bool a = (j <= MM) && (p[j] > 0);
    const unsigned long long mask = __ballot(a);
    const int rank = __popcll(mask & ((1ull << lane) - 1ull));
    if (a) {
      rows_out[b*NT + base + rank] = (float)(j - 1);
      cols_out[b*NT + base + rank] = (float)(p[j] - 1);
    }
    base += __popcll(mask);
  }
}

extern "C" void kernel_launch(void* const* d_in, const int* in_sizes, int n_in,
                              void* d_out, int out_size, void* d_ws, size_t ws_size,
                              hipStream_t stream) {
  const float* logits = (const float*)d_in[0];
  const float* boxes  = (const float*)d_in[1];
  const int*   labels = (const int*)d_in[2];
  const float* tbox   = (const float*)d_in[3];

  float* C    = (float*)d_out;
  float* rows = C + (size_t)BSZ * NQ * SUMT;
  float* cols = rows + (size_t)BSZ * NT;

  const size_t needT = (size_t)SUMT * MM * sizeof(float);        // ~14.7 MB
  const size_t needP = (size_t)BSZ * NQ * NCL * sizeof(float);   // ~5.3 MB

  if (ws_size >= needP + needT) {
    float* P     = (float*)d_ws;
    float* costT = P + (size_t)BSZ * NQ * NCL;
    hipLaunchKernelGGL(prob_kernel, dim3(BSZ*NQ/4), dim3(256), 0, stream, logits, P);
    hipLaunchKernelGGL(cost_kernel2, dim3(SUMT/256, NQ/QCHUNK, BSZ), dim3(256), 0, stream,
                       P, boxes, labels, tbox, C);
    hipLaunchKernelGGL(transpose_kernel, dim3(15, 4, BSZ), dim3(256), 0, stream, C, costT);
    hipLaunchKernelGGL(lsa_kernel, dim3(BSZ), dim3(256), 0, stream, C, costT, rows, cols);
  } else if (ws_size >= needT) {
    float* costT = (float*)d_ws;
    hipLaunchKernelGGL(cost_kernel_fb, dim3(BSZ*NQ), dim3(256), 0, stream,
                       logits, boxes, labels, tbox, C, costT);
    hipLaunchKernelGGL(lsa_kernel, dim3(BSZ), dim3(256), 0, stream, C, costT, rows, cols);
  } else {
    hipLaunchKernelGGL(cost_kernel_fb, dim3(BSZ*NQ), dim3(256), 0, stream,
                       logits, boxes, labels, tbox, C, (float*)nullptr);
    hipLaunchKernelGGL(lsa_kernel, dim3(BSZ), dim3(256), 0, stream,
                       C, (float*)nullptr, rows, cols);
  }
}